// Round 20
// baseline (1604.492 us; speedup 1.0000x reference)
//
#include <hip/hip_runtime.h>
#include <cmath>
#include <complex>
#include <vector>
#include <cstring>

// ============================ host: Wigner-3j tables ============================
static double hfact(int n){ double r=1; for(int i=2;i<=n;i++) r*=i; return r; }

static double hcg(int l1,int m1,int l2,int m2,int l3,int m3){
  if(m3!=m1+m2) return 0.0;
  double pre = std::sqrt((2*l3+1)*hfact(l3+l1-l2)*hfact(l3-l1+l2)*hfact(l1+l2-l3)/hfact(l1+l2+l3+1));
  pre *= std::sqrt(hfact(l3+m3)*hfact(l3-m3)*hfact(l1-m1)*hfact(l1+m1)*hfact(l2-m2)*hfact(l2+m2));
  double s=0;
  for(int k=0;k<=l1+l2-l3;k++){
    int d0=k,d1=l1+l2-l3-k,d2=l1-m1-k,d3=l2+m2-k,d4=l3-l2+m1+k,d5=l3-l1-m2+k;
    if(d0<0||d1<0||d2<0||d3<0||d4<0||d5<0) continue;
    double den=hfact(d0)*hfact(d1)*hfact(d2)*hfact(d3)*hfact(d4)*hfact(d5);
    s += ((k&1)?-1.0:1.0)/den;
  }
  return pre*s;
}

static void hU(int l, std::complex<double>* U){
  int n=2*l+1;
  for(int i=0;i<n*n;i++) U[i]=std::complex<double>(0.0,0.0);
  U[l*n+l]=1.0;
  double s2=std::sqrt(0.5);
  for(int m=1;m<=l;m++){
    double sgn=(m&1)?-1.0:1.0;
    U[(l+m)*n+(l+m)] = sgn*s2;
    U[(l+m)*n+(l-m)] = s2;
    U[(l-m)*n+(l-m)] = std::complex<double>(0.0, s2);
    U[(l-m)*n+(l+m)] = std::complex<double>(0.0, -sgn*s2);
  }
}

static void real_w3j(int l1,int l2,int l3, float* out){
  int n1=2*l1+1,n2=2*l2+1,n3=2*l3+1;
  std::vector<double> w((size_t)n1*n2*n3,0.0);
  for(int m1=-l1;m1<=l1;m1++)for(int m2=-l2;m2<=l2;m2++){
    int m3=-(m1+m2);
    if(m3<-l3||m3>l3) continue;
    int e=l1-l2-m3;
    double sgn = (((e%2)+2)%2)?-1.0:1.0;
    w[((size_t)(m1+l1)*n2+(m2+l2))*n3+(m3+l3)] = sgn*hcg(l1,m1,l2,m2,l3,-m3)/std::sqrt((double)(2*l3+1));
  }
  std::vector<std::complex<double>> U1((size_t)n1*n1),U2((size_t)n2*n2),U3((size_t)n3*n3),R((size_t)n1*n2*n3,std::complex<double>(0,0));
  hU(l1,U1.data()); hU(l2,U2.data()); hU(l3,U3.data());
  for(int i=0;i<n1;i++)for(int j=0;j<n2;j++)for(int k=0;k<n3;k++){
    std::complex<double> acc(0.0,0.0);
    for(int m=0;m<n1;m++){
      std::complex<double> u1=U1[i*n1+m]; if(u1.real()==0.0&&u1.imag()==0.0) continue;
      for(int nn=0;nn<n2;nn++){
        std::complex<double> u2=U2[j*n2+nn]; if(u2.real()==0.0&&u2.imag()==0.0) continue;
        std::complex<double> u12=u1*u2;
        for(int o=0;o<n3;o++){
          double wv=w[((size_t)m*n2+nn)*n3+o];
          if(wv!=0.0) acc += u12*U3[k*n3+o]*wv;
        }
      }
    }
    R[((size_t)i*n2+j)*n3+k]=acc;
  }
  double mre=0,mim=0;
  for(size_t t=0;t<R.size();t++){ mre=std::max(mre,std::fabs(R[t].real())); mim=std::max(mim,std::fabs(R[t].imag())); }
  bool useRe = (mre>=mim);
  double nrm=0;
  for(size_t t=0;t<R.size();t++){ double v=useRe?R[t].real():R[t].imag(); nrm+=v*v; }
  nrm=std::sqrt(nrm);
  for(size_t t=0;t<R.size();t++){ double v=useRe?R[t].real():R[t].imag(); out[t]=(float)(v/nrm); }
}

// All 11 interaction-path W3J tables (kernarg). (0,l,l)/(l,0,l)/(l,l,0) are diagonal.
struct WAll {
  float w000;
  float w011[9];
  float w022[25];
  float w101[9];
  float w110[9];
  float w112[45];
  float w121[45];
  float w202[25];
  float w211[45];
  float w220[25];
  float w222[125];
};
struct Wg { float w000; float w022[25]; float w202[25]; float w220[25]; float w222[125]; float w224[225]; };

// ============================ device helpers ============================
__device__ __forceinline__ float bcast(float v, int l){
  return __int_as_float(__builtin_amdgcn_readlane(__float_as_int(v), l));
}
__device__ __forceinline__ float silu(float x){ return x/(1.f+expf(-x)); }

// ============================ k_prep ============================
__global__ __launch_bounds__(256) void k_prep(
  const float* __restrict__ We, const float* __restrict__ be, const float* __restrict__ up1,
  const float* __restrict__ lin1, const float* __restrict__ lin1b, const float* __restrict__ up2,
  float* __restrict__ M123, float* __restrict__ Svec, float* __restrict__ Tvec, float* __restrict__ bias2)
{
  int idx=blockIdx.x*256+threadIdx.x;
  if(idx<12288){
    int l=idx>>12, c=(idx>>6)&63, d=idx&63;
    float a=0;
    for(int k=0;k<64;k++) a+=lin1[l*4096+c*64+k]*up2[l*4096+k*64+d];
    M123[idx]=0.1f*a;
  } else if(idx<12352){
    int d=idx-12288; float a=0;
    for(int c=0;c<64;c++) a+=We[c]*up1[c*64+d];
    Svec[d]=a;
  } else if(idx<12416){
    int d=idx-12352; float a=0;
    for(int c=0;c<64;c++) a+=be[c]*up1[c*64+d];
    Tvec[d]=a;
  } else if(idx<12480){
    int d=idx-12416; float a=0;
    for(int c=0;c<64;c++) a+=lin1b[c]*up2[c*64+d];
    bias2[d]=a;
  }
}

// k_shuf: T1 [(h*64+c)*4+p] ; T2 quad-planes [((h*3+q)*64+c)*4+j] = w[h][(4q+j)*64+c]
__global__ __launch_bounds__(256) void k_shuf(
  const float* __restrict__ w2a, const float* __restrict__ w2b,
  float* __restrict__ T1, float* __restrict__ T2)
{
  int idx=blockIdx.x*256+threadIdx.x;
  if(idx<16384){
    int p=idx&3, c=(idx>>2)&63, h=idx>>8;
    T1[idx]=(p<3)? w2a[h*192+p*64+c] : 0.f;
  } else if(idx<16384+49152){
    int q2=idx-16384;
    int h=q2/768, rem=q2%768, qq=rem>>8, rem2=rem&255, c=rem2>>2, j=rem2&3;
    int p=qq*4+j;
    T2[q2]=(p<11)? w2b[h*704+p*64+c] : 0.f;
  }
}

// ============================ counting sort by receiver ============================
__global__ __launch_bounds__(256) void k_hist(const int* __restrict__ eidx, int* __restrict__ hist, int E){
  int e=blockIdx.x*256+threadIdx.x;
  if(e<E) atomicAdd(&hist[eidx[E+e]], 1);
}

// in-place exclusive scan: 256 threads, chunk-per-thread, one LDS scan of totals
__global__ __launch_bounds__(256) void k_scan(int* __restrict__ ho, int N){
  __shared__ int tsum[256];
  int tid=threadIdx.x;
  int chunk=(N+255)/256;
  int lo=tid*chunk; if(lo>N) lo=N;
  int hi=lo+chunk; if(hi>N) hi=N;
  int s=0;
  for(int i=lo;i<hi;i++) s+=ho[i];
  tsum[tid]=s;
  __syncthreads();
  for(int off=1;off<256;off<<=1){
    int add=(tid>=off)? tsum[tid-off]:0;
    __syncthreads();
    tsum[tid]+=add;
    __syncthreads();
  }
  int base=(tid==0)?0:tsum[tid-1];
  for(int i=lo;i<hi;i++){
    int v=ho[i];
    ho[i]=base;
    base+=v;
  }
}

__global__ __launch_bounds__(256) void k_scatter(
  const int* __restrict__ eidx, int* __restrict__ offs,
  int* __restrict__ posOf, int* __restrict__ sndS, int* __restrict__ rcvS, int E)
{
  int e=blockIdx.x*256+threadIdx.x;
  if(e<E){
    int r=eidx[E+e];
    int pos=atomicAdd(&offs[r],1);
    posOf[e]=pos;
    sndS[pos]=eidx[e];
    rcvS[pos]=r;
  }
}

// ============================ k_geom (writes receiver-sorted slots) ============
__global__ __launch_bounds__(256) void k_geom(
  const float* __restrict__ pos, const float* __restrict__ shifts,
  const float* __restrict__ eattr, const int* __restrict__ eidx,
  const int* __restrict__ posOf,
  float* __restrict__ shb, float* __restrict__ efb, float* __restrict__ Tbl,
  int E, WAll W)
{
  int e=blockIdx.x*256+threadIdx.x;
  if(e>=E) return;
  int s=eidx[e], r=eidx[E+e];
  int ps=posOf[e];
  float vx=pos[r*3+0]-pos[s*3+0]+shifts[e*3+0];
  float vy=pos[r*3+1]-pos[s*3+1]+shifts[e*3+1];
  float vz=pos[r*3+2]-pos[s*3+2]+shifts[e*3+2];
  float len=sqrtf(vx*vx+vy*vy+vz*vz);
  float inv=1.f/(len+1e-9f);
  float x=vx*inv,y=vy*inv,z=vz*inv;
  const float c3=1.7320508075688772f, c15=3.872983346207417f, c5h=1.118033988749895f, c15h=1.9364916731037085f;
  float s1[3]={c3*x, c3*y, c3*z};
  float s2[5]={c15*x*y, c15*y*z, c5h*(3.f*z*z-1.f), c15*x*z, c15h*(x*x-y*y)};
  float* sp=&shb[(size_t)ps*12];
  sp[0]=1.f; sp[1]=s1[0]; sp[2]=s1[1]; sp[3]=s1[2];
  sp[4]=s2[0]; sp[5]=s2[1]; sp[6]=s2[2]; sp[7]=s2[3]; sp[8]=s2[4];
  sp[9]=0.f; sp[10]=0.f; sp[11]=0.f;
  float ea=eattr[e];
  float* fp=&efb[(size_t)ps*12];
  #pragma unroll
  for(int i=0;i<6;i++){ float d=(len-0.12f*(float)i)/0.12f; fp[i]=expf(-d*d)/1.12f; }
  #pragma unroll
  for(int i=0;i<6;i++){ float d=(ea-0.006f*(float)i)/0.006f; fp[6+i]=expf(-d*d)/1.12f; }
  if(Tbl){
    float* tb=&Tbl[(size_t)ps*96];
    #pragma unroll
    for(int k=0;k<3;k++) tb[k]=s1[k]*W.w011[k*4];
    tb[3]=0.f;
    #pragma unroll
    for(int k=0;k<5;k++) tb[4+k]=s2[k]*W.w022[k*6];
    tb[9]=0.f; tb[10]=0.f; tb[11]=0.f;
    #pragma unroll
    for(int i=0;i<3;i++) tb[12+i]=s1[i]*W.w110[i*4];
    tb[15]=0.f;
    #pragma unroll
    for(int i=0;i<5;i++) tb[16+i]=s2[i]*W.w220[i*6];
    tb[21]=0.f; tb[22]=0.f; tb[23]=0.f;
    #pragma unroll
    for(int i=0;i<3;i++)
      #pragma unroll
      for(int k=0;k<3;k++){ float t=0;
        #pragma unroll
        for(int j=0;j<5;j++) t+=s2[j]*W.w121[(i*5+j)*3+k];
        tb[24+i*3+k]=t; }
    tb[33]=0.f; tb[34]=0.f; tb[35]=0.f;
    #pragma unroll
    for(int i=0;i<5;i++)
      #pragma unroll
      for(int k=0;k<3;k++){ float t=0;
        #pragma unroll
        for(int j=0;j<3;j++) t+=s1[j]*W.w211[(i*3+j)*3+k];
        tb[36+i*3+k]=t; }
    tb[51]=0.f;
    #pragma unroll
    for(int i=0;i<3;i++)
      #pragma unroll
      for(int k=0;k<5;k++){ float t=0;
        #pragma unroll
        for(int j=0;j<3;j++) t+=s1[j]*W.w112[(i*3+j)*5+k];
        tb[52+i*5+k]=t; }
    tb[67]=0.f;
    #pragma unroll
    for(int i=0;i<5;i++)
      #pragma unroll
      for(int k=0;k<5;k++){ float t=0;
        #pragma unroll
        for(int j=0;j<5;j++) t+=s2[j]*W.w222[(i*5+j)*5+k];
        tb[68+i*5+k]=t; }
    tb[93]=0.f; tb[94]=0.f; tb[95]=0.f;
  }
}

// ============================ k_edge1: chunked-LDS b128, sorted + run-merged ============
template<int TBL>
__global__ __launch_bounds__(256) void k_edge1(
  const float* __restrict__ na, const float* __restrict__ SV, const float* __restrict__ TV,
  const float* __restrict__ m1, const float* __restrict__ m2T,
  const float* __restrict__ sh, const float* __restrict__ Tbl, const float* __restrict__ ef,
  const int* __restrict__ sndS, const int* __restrict__ rcvS,
  float* __restrict__ agg, int E, WAll W)
{
  __shared__ __align__(16) float wl[8*256];
  __shared__ float m1s[768];
  int tid=threadIdx.x, lane=tid&63, wid=tid>>6;
  for(int i=tid;i<768;i+=256) m1s[i]=m1[i];
  float Sv=SV[lane], Tv=TV[lane];
  __syncthreads();
  int nb=(E+31)/32;
  for(int b=blockIdx.x;b<nb;b+=gridDim.x){
    int e0=b*32+wid*8;
    float hid[8]; float acc[8][3];
    #pragma unroll
    for(int e=0;e<8;e++){
      float h=0.f;
      if(e0+e<E){
        const float4* fp=(const float4*)(ef+(size_t)(e0+e)*12);
        float4 f0=fp[0], f1=fp[1], f2=fp[2];
        h = f0.x*m1s[0*64+lane]+f0.y*m1s[1*64+lane]+f0.z*m1s[2*64+lane]+f0.w*m1s[3*64+lane]
          + f1.x*m1s[4*64+lane]+f1.y*m1s[5*64+lane]+f1.z*m1s[6*64+lane]+f1.w*m1s[7*64+lane]
          + f2.x*m1s[8*64+lane]+f2.y*m1s[9*64+lane]+f2.z*m1s[10*64+lane]+f2.w*m1s[11*64+lane];
      }
      hid[e]=silu(h);
      acc[e][0]=0; acc[e][1]=0; acc[e][2]=0;
    }
    for(int ch=0;ch<8;ch++){
      __syncthreads();
      const float4* src=(const float4*)(m2T+(size_t)ch*2048);
      float4* dst4=(float4*)wl;
      dst4[tid]=src[tid];
      dst4[tid+256]=src[tid+256];
      __syncthreads();
      #pragma unroll
      for(int h8=0;h8<8;h8++){
        int h=ch*8+h8;
        float4 mv=*(const float4*)&wl[(h8*64+lane)*4];
        #pragma unroll
        for(int e=0;e<8;e++){
          float s=bcast(hid[e],h);
          acc[e][0]+=s*mv.x; acc[e][1]+=s*mv.y; acc[e][2]+=s*mv.z;
        }
      }
    }
    // run-merged epilogue (rcvS non-decreasing)
    float carry[9];
    #pragma unroll
    for(int k=0;k<9;k++) carry[k]=0.f;
    int lastR=-1;
    #pragma unroll
    for(int e=0;e<8;e++){
      int ee=e0+e;
      if(ee>=E) break;
      int snd=sndS[ee], rcv=rcvS[ee];
      if(lastR>=0 && rcv!=lastR){
        float* dst=&agg[(size_t)lastR*576];
        atomicAdd(&dst[lane], carry[0]);
        #pragma unroll
        for(int k=0;k<3;k++) atomicAdd(&dst[(1+k)*64+lane], carry[1+k]);
        #pragma unroll
        for(int k=0;k<5;k++) atomicAdd(&dst[(4+k)*64+lane], carry[4+k]);
        #pragma unroll
        for(int k=0;k<9;k++) carry[k]=0.f;
      }
      float g0 = na[snd]*Sv + Tv;
      if constexpr(TBL){
        const float* tb=&Tbl[(size_t)ee*96];
        carry[0]+=g0*W.w000*acc[e][0];
        #pragma unroll
        for(int k=0;k<3;k++) carry[1+k]+=g0*acc[e][1]*tb[k];
        #pragma unroll
        for(int k=0;k<5;k++) carry[4+k]+=g0*acc[e][2]*tb[4+k];
      } else {
        const float4* shp=(const float4*)(sh+(size_t)ee*12);
        float4 h0=shp[0], h1=shp[1], h2=shp[2];
        float s1[3]={h0.y,h0.z,h0.w};
        float s2[5]={h1.x,h1.y,h1.z,h1.w,h2.x};
        carry[0]+=g0*W.w000*acc[e][0];
        #pragma unroll
        for(int k=0;k<3;k++) carry[1+k]+=g0*acc[e][1]*s1[k]*W.w011[k*4];
        #pragma unroll
        for(int k=0;k<5;k++) carry[4+k]+=g0*acc[e][2]*s2[k]*W.w022[k*6];
      }
      lastR=rcv;
    }
    if(lastR>=0){
      float* dst=&agg[(size_t)lastR*576];
      atomicAdd(&dst[lane], carry[0]);
      #pragma unroll
      for(int k=0;k<3;k++) atomicAdd(&dst[(1+k)*64+lane], carry[1+k]);
      #pragma unroll
      for(int k=0;k<5;k++) atomicAdd(&dst[(4+k)*64+lane], carry[4+k]);
    }
  }
}

// ============================ k_edge2: chunked-LDS quad-plane, sorted + run-merged ====
template<int TBL>
__global__ __launch_bounds__(256) void k_edge2(
  const float* __restrict__ ups2, const float* __restrict__ m1, const float* __restrict__ m2T,
  const float* __restrict__ sh, const float* __restrict__ Tbl, const float* __restrict__ ef,
  const int* __restrict__ sndS, const int* __restrict__ rcvS,
  float* __restrict__ agg, int E, WAll W)
{
  __shared__ __align__(16) float wl[8*768];
  __shared__ float m1s[768];
  int tid=threadIdx.x, lane=tid&63, wid=tid>>6;
  for(int i=tid;i<768;i+=256) m1s[i]=m1[i];
  __syncthreads();
  int nb=(E+15)/16;
  for(int b=blockIdx.x;b<nb;b+=gridDim.x){
    int e0=b*16+wid*4;
    float hid[4]; float acc[4][11];
    #pragma unroll
    for(int e=0;e<4;e++){
      float h=0.f;
      if(e0+e<E){
        const float4* fp=(const float4*)(ef+(size_t)(e0+e)*12);
        float4 f0=fp[0], f1=fp[1], f2=fp[2];
        h = f0.x*m1s[0*64+lane]+f0.y*m1s[1*64+lane]+f0.z*m1s[2*64+lane]+f0.w*m1s[3*64+lane]
          + f1.x*m1s[4*64+lane]+f1.y*m1s[5*64+lane]+f1.z*m1s[6*64+lane]+f1.w*m1s[7*64+lane]
          + f2.x*m1s[8*64+lane]+f2.y*m1s[9*64+lane]+f2.z*m1s[10*64+lane]+f2.w*m1s[11*64+lane];
      }
      hid[e]=silu(h);
      #pragma unroll
      for(int p=0;p<11;p++) acc[e][p]=0.f;
    }
    for(int ch=0;ch<8;ch++){
      __syncthreads();
      const float4* src=(const float4*)(m2T+(size_t)ch*6144);
      float4* dst4=(float4*)wl;
      #pragma unroll
      for(int i=0;i<6;i++) dst4[tid+i*256]=src[tid+i*256];
      __syncthreads();
      #pragma unroll
      for(int h8=0;h8<8;h8++){
        int h=ch*8+h8;
        float4 q0=*(const float4*)&wl[((h8*3+0)*64+lane)*4];
        float4 q1=*(const float4*)&wl[((h8*3+1)*64+lane)*4];
        float4 q2=*(const float4*)&wl[((h8*3+2)*64+lane)*4];
        #pragma unroll
        for(int e=0;e<4;e++){
          float s=bcast(hid[e],h);
          acc[e][0]+=s*q0.x; acc[e][1]+=s*q0.y; acc[e][2]+=s*q0.z; acc[e][3]+=s*q0.w;
          acc[e][4]+=s*q1.x; acc[e][5]+=s*q1.y; acc[e][6]+=s*q1.z; acc[e][7]+=s*q1.w;
          acc[e][8]+=s*q2.x; acc[e][9]+=s*q2.y; acc[e][10]+=s*q2.z;
        }
      }
    }
    // run-merged epilogue (rcvS non-decreasing)
    float carry[9];
    #pragma unroll
    for(int k=0;k<9;k++) carry[k]=0.f;
    int lastR=-1;
    #pragma unroll
    for(int e=0;e<4;e++){
      int ee=e0+e;
      if(ee>=E) break;
      int snd=sndS[ee], rcv=rcvS[ee];
      if(lastR>=0 && rcv!=lastR){
        float* dst=&agg[(size_t)lastR*576];
        atomicAdd(&dst[lane], carry[0]);
        #pragma unroll
        for(int k=0;k<3;k++) atomicAdd(&dst[(1+k)*64+lane], carry[1+k]);
        #pragma unroll
        for(int k=0;k<5;k++) atomicAdd(&dst[(4+k)*64+lane], carry[4+k]);
        #pragma unroll
        for(int k=0;k<9;k++) carry[k]=0.f;
      }
      const float* up=&ups2[(size_t)snd*576];
      float a0=acc[e][0],a1=acc[e][1],a2=acc[e][2],a3=acc[e][3];
      float a4=acc[e][4],a5=acc[e][5],a6=acc[e][6],a7=acc[e][7];
      float a8=acc[e][8],a9=acc[e][9],a10=acc[e][10];
      float g0=up[lane];
      float g1[3], g2[5];
      #pragma unroll
      for(int i=0;i<3;i++) g1[i]=up[(1+i)*64+lane];
      #pragma unroll
      for(int i=0;i<5;i++) g2[i]=up[(4+i)*64+lane];
      if constexpr(TBL){
        const float* tb=&Tbl[(size_t)ee*96];
        {
          float t110 = g1[0]*tb[12]+g1[1]*tb[13]+g1[2]*tb[14];
          float t220 = g2[0]*tb[16]+g2[1]*tb[17]+g2[2]*tb[18]+g2[3]*tb[19]+g2[4]*tb[20];
          carry[0] += W.w000*g0*a0 + a4*t110 + a9*t220;
        }
        #pragma unroll
        for(int k=0;k<3;k++){
          float t121 = g1[0]*tb[24+k]+g1[1]*tb[27+k]+g1[2]*tb[30+k];
          float t211 = g2[0]*tb[36+k]+g2[1]*tb[39+k]+g2[2]*tb[42+k]+g2[3]*tb[45+k]+g2[4]*tb[48+k];
          carry[1+k] += g0*a1*tb[k] + a3*g1[k]*W.w101[k*4] + a6*t121 + a8*t211;
        }
        #pragma unroll
        for(int k=0;k<5;k++){
          float t112 = g1[0]*tb[52+k]+g1[1]*tb[57+k]+g1[2]*tb[62+k];
          float t222 = g2[0]*tb[68+k]+g2[1]*tb[73+k]+g2[2]*tb[78+k]+g2[3]*tb[83+k]+g2[4]*tb[88+k];
          carry[4+k] += g0*a2*tb[4+k] + a7*g2[k]*W.w202[k*6] + a5*t112 + a10*t222;
        }
      } else {
        const float4* shp=(const float4*)(sh+(size_t)ee*12);
        float4 h0=shp[0], h1=shp[1], h2=shp[2];
        float s1[3]={h0.y,h0.z,h0.w};
        float s2[5]={h1.x,h1.y,h1.z,h1.w,h2.x};
        {
          float t110 = g1[0]*s1[0]*W.w110[0]+g1[1]*s1[1]*W.w110[4]+g1[2]*s1[2]*W.w110[8];
          float t220 = 0;
          #pragma unroll
          for(int i=0;i<5;i++) t220 += g2[i]*s2[i]*W.w220[i*6];
          carry[0] += W.w000*g0*a0 + a4*t110 + a9*t220;
        }
        #pragma unroll
        for(int k=0;k<3;k++){
          float mk = g0*a1*s1[k]*W.w011[k*4];
          mk += a3*g1[k]*W.w101[k*4];
          float t=0;
          #pragma unroll
          for(int i=0;i<3;i++){ float u=0;
            #pragma unroll
            for(int j=0;j<5;j++) u+=s2[j]*W.w121[(i*5+j)*3+k];
            t+=g1[i]*u; }
          mk += a6*t;
          t=0;
          #pragma unroll
          for(int i=0;i<5;i++){ float u=0;
            #pragma unroll
            for(int j=0;j<3;j++) u+=s1[j]*W.w211[(i*3+j)*3+k];
            t+=g2[i]*u; }
          mk += a8*t;
          carry[1+k]+=mk;
        }
        #pragma unroll
        for(int k=0;k<5;k++){
          float mk = g0*a2*s2[k]*W.w022[k*6];
          float t=0;
          #pragma unroll
          for(int i=0;i<3;i++){ float u=0;
            #pragma unroll
            for(int j=0;j<3;j++) u+=s1[j]*W.w112[(i*3+j)*5+k];
            t+=g1[i]*u; }
          mk += a5*t;
          mk += a7*g2[k]*W.w202[k*6];
          t=0;
          #pragma unroll
          for(int i=0;i<5;i++){ float u=0;
            #pragma unroll
            for(int j=0;j<5;j++) u+=s2[j]*W.w222[(i*5+j)*5+k];
            t+=g2[i]*u; }
          mk += a10*t;
          carry[4+k]+=mk;
        }
      }
      lastR=rcv;
    }
    if(lastR>=0){
      float* dst=&agg[(size_t)lastR*576];
      atomicAdd(&dst[lane], carry[0]);
      #pragma unroll
      for(int k=0;k<3;k++) atomicAdd(&dst[(1+k)*64+lane], carry[1+k]);
      #pragma unroll
      for(int k=0;k<5;k++) atomicAdd(&dst[(4+k)*64+lane], carry[4+k]);
    }
  }
}

// ============================ k_node<MODE> ============================
template<int MODE>
__global__ __launch_bounds__(256) void k_node(
  const float* __restrict__ X, float* __restrict__ Y,
  const float* __restrict__ Ms, const float* __restrict__ bias,
  const float* __restrict__ gates, const int* __restrict__ batch,
  int N, float scale)
{
  int kk=blockIdx.y;
  int l=(kk==0)?0:(kk<4)?1:2;
  __shared__ float Mt[64][68];
  const float* M=Ms+l*4096;
  int tid=threadIdx.x;
  for(int idx=tid;idx<4096;idx+=256){ int c=idx>>6,d=idx&63; Mt[d][c]=M[idx]; }
  __syncthreads();
  int lane=tid&63, wid=tid>>6;
  int n0=(blockIdx.x*4+wid)*4;
  float xr[4];
  #pragma unroll
  for(int t=0;t<4;t++){ int n=n0+t; xr[t]=(n<N)?X[(size_t)n*576+kk*64+lane]:0.f; }
  float acc[4]={0,0,0,0};
  for(int cb=0;cb<64;cb+=4){
    float4 mv=*(const float4*)&Mt[lane][cb];
    #pragma unroll
    for(int t=0;t<4;t++){
      acc[t]+=bcast(xr[t],cb+0)*mv.x;
      acc[t]+=bcast(xr[t],cb+1)*mv.y;
      acc[t]+=bcast(xr[t],cb+2)*mv.z;
      acc[t]+=bcast(xr[t],cb+3)*mv.w;
    }
  }
  #pragma unroll
  for(int t=0;t<4;t++){
    int n=n0+t; if(n>=N) break;
    float v=acc[t]*scale;
    if constexpr(MODE==0||MODE==1){
      if(kk==0) v+=bias[lane];
      Y[(size_t)n*576+kk*64+lane]=v;
    } else if constexpr(MODE==2){
      if(kk==0) v=silu(v);
      else if(kk<4) v*=gates[(size_t)n*128+lane];
      else v*=gates[(size_t)n*128+64+lane];
      Y[(size_t)n*576+kk*64+lane]=v;
    } else {
      int bg=batch[n];
      atomicAdd(&Y[(size_t)bg*576+kk*64+lane], v);
    }
  }
}

// ============ k_node_fused: xs=0.1*X@lin2(+b) ; gates=silu(xs0@gw+gb) ; Y=act(xs@rolin) ============
// In-place safe (X==Y): each block reads only its own 16 rows, all reads precede writes.
__global__ __launch_bounds__(256) void k_node_fused(
  const float* __restrict__ X, float* __restrict__ Y,
  const float* __restrict__ lin2, const float* __restrict__ lin2b,
  const float* __restrict__ gw, const float* __restrict__ gb,
  const float* __restrict__ rolin, int N)
{
  __shared__ float Wt[128][68];
  int tid=threadIdx.x, lane=tid&63, wid=tid>>6;
  int n0=(blockIdx.x*4+wid)*4;
  float xs[4][9];
  float b0=lin2b[lane];
  // ---- phase 1: xs (registers) ----
  #pragma unroll
  for(int l=0;l<3;l++){
    __syncthreads();
    {
      const float* M=lin2+l*4096;
      for(int idx=tid;idx<4096;idx+=256){ int c=idx>>6,d=idx&63; Wt[d][c]=M[idx]; }
    }
    __syncthreads();
    const int kk0 = (l==0)?0:(l==1)?1:4;
    const int kk1 = (l==0)?1:(l==1)?4:9;
    #pragma unroll
    for(int kk=kk0;kk<kk1;kk++){
      float xr[4];
      #pragma unroll
      for(int t=0;t<4;t++){ int n=n0+t; xr[t]=(n<N)?X[(size_t)n*576+kk*64+lane]:0.f; }
      float acc[4]={0,0,0,0};
      for(int cb=0;cb<64;cb+=4){
        float4 mv=*(const float4*)&Wt[lane][cb];
        #pragma unroll
        for(int t=0;t<4;t++){
          acc[t]+=bcast(xr[t],cb+0)*mv.x;
          acc[t]+=bcast(xr[t],cb+1)*mv.y;
          acc[t]+=bcast(xr[t],cb+2)*mv.z;
          acc[t]+=bcast(xr[t],cb+3)*mv.w;
        }
      }
      #pragma unroll
      for(int t=0;t<4;t++){
        float v=acc[t]*0.1f;
        if(kk==0) v+=b0;
        xs[t][kk]=v;
      }
    }
  }
  // ---- phase 2: gates ----
  __syncthreads();
  for(int idx=tid; idx<8192; idx+=256){ int c=idx>>7, t=idx&127; Wt[t][c]=gw[c*128+t]; }
  __syncthreads();
  float gA[4], gB[4];
  {
    float a0[4]={0,0,0,0}, a1[4]={0,0,0,0};
    for(int cb=0;cb<64;cb+=4){
      float4 m0=*(const float4*)&Wt[lane][cb];
      float4 m1=*(const float4*)&Wt[64+lane][cb];
      #pragma unroll
      for(int t=0;t<4;t++){
        float x0=bcast(xs[t][0],cb), x1=bcast(xs[t][0],cb+1), x2=bcast(xs[t][0],cb+2), x3=bcast(xs[t][0],cb+3);
        a0[t]+=x0*m0.x+x1*m0.y+x2*m0.z+x3*m0.w;
        a1[t]+=x0*m1.x+x1*m1.y+x2*m1.z+x3*m1.w;
      }
    }
    float gb0=gb[lane], gb1=gb[64+lane];
    #pragma unroll
    for(int t=0;t<4;t++){ gA[t]=silu(a0[t]+gb0); gB[t]=silu(a1[t]+gb1); }
  }
  // ---- phase 3: y = act(xs @ rolin) ----
  #pragma unroll
  for(int l=0;l<3;l++){
    __syncthreads();
    {
      const float* M=rolin+l*4096;
      for(int idx=tid;idx<4096;idx+=256){ int c=idx>>6,d=idx&63; Wt[d][c]=M[idx]; }
    }
    __syncthreads();
    const int kk0 = (l==0)?0:(l==1)?1:4;
    const int kk1 = (l==0)?1:(l==1)?4:9;
    #pragma unroll
    for(int kk=kk0;kk<kk1;kk++){
      float acc[4]={0,0,0,0};
      for(int cb=0;cb<64;cb+=4){
        float4 mv=*(const float4*)&Wt[lane][cb];
        #pragma unroll
        for(int t=0;t<4;t++){
          acc[t]+=bcast(xs[t][kk],cb+0)*mv.x;
          acc[t]+=bcast(xs[t][kk],cb+1)*mv.y;
          acc[t]+=bcast(xs[t][kk],cb+2)*mv.z;
          acc[t]+=bcast(xs[t][kk],cb+3)*mv.w;
        }
      }
      #pragma unroll
      for(int t=0;t<4;t++){
        int n=n0+t; if(n>=N) continue;
        float v=acc[t];
        if(kk==0) v=silu(v);
        else if(kk<4) v*=gA[t];
        else v*=gB[t];
        Y[(size_t)n*576+kk*64+lane]=v;
      }
    }
  }
}

// ============================ k_cnt ============================
__global__ __launch_bounds__(256) void k_cnt(const int* __restrict__ batch, float* __restrict__ cnt, int N){
  int n=blockIdx.x*256+threadIdx.x;
  if(n<N) atomicAdd(&cnt[batch[n]], 1.f);
}

// ============================ k_graph ============================
__device__ void ctp_dev(const float* a0, const float* a2, const float* b0, const float* b2,
                        const float* pw, float* o0, float* o2, int c, const Wg& W)
{
  float A0=a0[c], B0=b0[c], A2[5], B2[5];
  #pragma unroll
  for(int i=0;i<5;i++){ A2[i]=a2[c*5+i]; B2[i]=b2[c*5+i]; }
  float o = pw[0*16+c]*A0*B0*W.w000;
  { float t=0;
    #pragma unroll
    for(int i=0;i<5;i++)
      #pragma unroll
      for(int j=0;j<5;j++) t+=A2[i]*B2[j]*W.w220[i*5+j];
    o += pw[3*16+c]*t; }
  o0[c]=o;
  #pragma unroll
  for(int k=0;k<5;k++){
    float t=0;
    { float s=0;
      #pragma unroll
      for(int j=0;j<5;j++) s+=B2[j]*W.w022[j*5+k];
      t+=pw[1*16+c]*A0*s; }
    { float s=0;
      #pragma unroll
      for(int i=0;i<5;i++) s+=A2[i]*W.w202[i*5+k];
      t+=pw[2*16+c]*s*B0; }
    { float s=0;
      #pragma unroll
      for(int i=0;i<5;i++)
        #pragma unroll
        for(int j=0;j<5;j++) s+=A2[i]*B2[j]*W.w222[(i*5+j)*5+k];
      t+=pw[4*16+c]*s; }
    o2[c*5+k]=t;
  }
}

__global__ __launch_bounds__(256) void k_graph(
  const float* __restrict__ gsum, const float* __restrict__ cnt,
  const float* __restrict__ glin_w0, const float* __restrict__ glin_b0, const float* __restrict__ glin_w2,
  const float* __restrict__ pw2, const float* __restrict__ pw3, const float* __restrict__ PL,
  const float* __restrict__ fo_w, float* __restrict__ out, Wg W)
{
  int g=blockIdx.x, tid=threadIdx.x;
  __shared__ float g0[64], g2[64*5];
  __shared__ float r0[16], r2[16*5];
  __shared__ float t20[16], t22[16*5];
  __shared__ float t30[16], t32[16*5];
  __shared__ float rp0[16], rp2[16*5];
  __shared__ float outs0[2], outs2[10], outs4[9];
  __shared__ float vv[21], stf[81], Cm[36];
  __shared__ float B21s[21*81];

  if(tid<21){
    const int pi[6]={0,1,2,1,0,0}, pj[6]={0,1,2,2,2,1};
    int a=0,b=0,idx=tid;
    for(a=0;a<6;a++){ int c6=6-a; if(idx<c6){ b=a+idx; break; } idx-=c6; }
    float ma[9]; float mb[9];
    for(int x=0;x<9;x++){ ma[x]=0; mb[x]=0; }
    { float v=(pi[a]==pj[a])?1.f:0.7071067811865476f; ma[pi[a]*3+pj[a]]=v; ma[pj[a]*3+pi[a]]=v; }
    { float v=(pi[b]==pj[b])?1.f:0.7071067811865476f; mb[pi[b]*3+pj[b]]=v; mb[pj[b]*3+pi[b]]=v; }
    float T[81]; float nrm=0;
    for(int x=0;x<81;x++){
      int ij=x/9, kl=x%9;
      float t=0.5f*(ma[ij]*mb[kl]+mb[ij]*ma[kl]);
      T[x]=t; nrm+=t*t;
    }
    nrm=sqrtf(nrm);
    for(int x=0;x<81;x++) B21s[tid*81+x]=T[x]/nrm;
  }

  float cinv=1.f/fmaxf(cnt[g],1.f);
  if(tid<64){
    g0[tid]=gsum[(size_t)g*576+tid]*cinv;
    for(int k=0;k<5;k++) g2[tid*5+k]=gsum[(size_t)g*576+(4+k)*64+tid]*cinv;
  }
  __syncthreads();

  if(tid<16){
    float a=0;
    for(int c=0;c<64;c++) a+=g0[c]*glin_w0[c*16+tid];
    r0[tid]=a+glin_b0[tid];
  } else if(tid<96){
    int u=(tid-16)/5, k=(tid-16)%5; float a=0;
    for(int c=0;c<64;c++) a+=g2[c*5+k]*glin_w2[c*16+u];
    r2[u*5+k]=a;
  }
  __syncthreads();

  if(tid<16) ctp_dev(r0,r2, r0,r2, pw2, t20,t22, tid, W);
  __syncthreads();
  if(tid<16) ctp_dev(t20,t22, r0,r2, pw3, t30,t32, tid, W);
  __syncthreads();

  if(tid<16){
    int d=tid; float a=0;
    for(int c=0;c<16;c++)
      a += r0[c]*PL[(0*2+0)*256+c*16+d] + t20[c]*PL[(1*2+0)*256+c*16+d] + t30[c]*PL[(2*2+0)*256+c*16+d];
    rp0[d]=a;
  } else if(tid<96){
    int q=tid-16, d=q/5, k=q%5; float a=0;
    for(int c=0;c<16;c++)
      a += r2[c*5+k]*PL[(0*2+1)*256+c*16+d] + t22[c*5+k]*PL[(1*2+1)*256+c*16+d] + t32[c*5+k]*PL[(2*2+1)*256+c*16+d];
    rp2[d*5+k]=a;
  }
  if(tid<2) outs0[tid]=0.f;
  else if(tid<12) outs2[tid-2]=0.f;
  else if(tid<21) outs4[tid-12]=0.f;
  __syncthreads();

  {
    int u=tid>>4, v=tid&15;
    float A0=rp0[u], B0=rp0[v], A2[5], B2[5];
    #pragma unroll
    for(int i=0;i<5;i++){ A2[i]=rp2[u*5+i]; B2[i]=rp2[v*5+i]; }
    float s00 = A0*B0*W.w000;
    float s220=0;
    #pragma unroll
    for(int i=0;i<5;i++)
      #pragma unroll
      for(int j=0;j<5;j++) s220+=A2[i]*B2[j]*W.w220[i*5+j];
    float s022[5], s202[5], s222[5], s224[9];
    #pragma unroll
    for(int k=0;k<5;k++){
      float s=0;
      #pragma unroll
      for(int j=0;j<5;j++) s+=B2[j]*W.w022[j*5+k];
      s022[k]=A0*s;
      float s2v=0;
      #pragma unroll
      for(int i=0;i<5;i++) s2v+=A2[i]*W.w202[i*5+k];
      s202[k]=s2v*B0;
      float s3v=0;
      #pragma unroll
      for(int i=0;i<5;i++)
        #pragma unroll
        for(int j=0;j<5;j++) s3v+=A2[i]*B2[j]*W.w222[(i*5+j)*5+k];
      s222[k]=s3v;
    }
    #pragma unroll
    for(int k=0;k<9;k++){
      float s=0;
      #pragma unroll
      for(int i=0;i<5;i++)
        #pragma unroll
        for(int j=0;j<5;j++) s+=A2[i]*B2[j]*W.w224[(i*5+j)*9+k];
      s224[k]=s;
    }
    #pragma unroll
    for(int w=0;w<2;w++){
      float f0=fo_w[((0*16+u)*16+v)*2+w], f1=fo_w[((1*16+u)*16+v)*2+w];
      float f2=fo_w[((2*16+u)*16+v)*2+w], f3=fo_w[((3*16+u)*16+v)*2+w];
      float f4=fo_w[((4*16+u)*16+v)*2+w];
      atomicAdd(&outs0[w], s00*f0 + s220*f1);
      #pragma unroll
      for(int k=0;k<5;k++)
        atomicAdd(&outs2[w*5+k], s022[k]*f2 + s202[k]*f3 + s222[k]*f4);
    }
    float f5=fo_w[((5*16+u)*16+v)*2+0];
    #pragma unroll
    for(int k=0;k<9;k++) atomicAdd(&outs4[k], s224[k]*f5);
  }
  __syncthreads();

  if(tid<2) vv[tid]=outs0[tid];
  else if(tid<12) vv[tid]=outs2[tid-2];
  else if(tid<21) vv[tid]=outs4[tid-12];
  __syncthreads();
  if(tid<81){
    float a=0;
    for(int q=0;q<21;q++) a+=vv[q]*B21s[q*81+tid];
    stf[tid]=a;
  }
  __syncthreads();
  {
    const int MI[6]={0,1,2,1,0,0}, MJ[6]={0,1,2,2,2,1};
    const float MF[6]={1.f,1.f,1.f,1.4142135623730951f,1.4142135623730951f,1.4142135623730951f};
    if(tid<36){
      int p=tid/6, q=tid%6;
      Cm[tid]=stf[MI[p]*27+MJ[p]*9+MI[q]*3+MJ[q]]*MF[p]*MF[q];
    }
  }
  __syncthreads();
  if(tid<36){
    int p=tid/6, q=tid%6; float a=0;
    for(int r=0;r<6;r++) a+=Cm[p*6+r]*Cm[r*6+q];
    out[(size_t)g*36+tid]=a;
  }
}

// ============================ kernel_launch ============================
extern "C" void kernel_launch(void* const* d_in, const int* in_sizes, int n_in,
                              void* d_out, int out_size, void* d_ws, size_t ws_size,
                              hipStream_t stream)
{
  const float* positions=(const float*)d_in[0];
  const float* node_attrs=(const float*)d_in[1];
  const float* edge_attr=(const float*)d_in[2];
  const float* shifts=(const float*)d_in[3];
  const float* W_embed=(const float*)d_in[4];
  const float* b_embed=(const float*)d_in[5];
  const float* up1_w=(const float*)d_in[6];
  const float* mlp1_w1=(const float*)d_in[7];
  const float* mlp1_w2=(const float*)d_in[8];
  const float* lin1_w=(const float*)d_in[9];
  const float* lin1_b=(const float*)d_in[10];
  const float* up2_w=(const float*)d_in[11];
  const float* mlp2_w1=(const float*)d_in[12];
  const float* mlp2_w2=(const float*)d_in[13];
  const float* lin2_w=(const float*)d_in[14];
  const float* lin2_b=(const float*)d_in[15];
  const float* ro_lin_w=(const float*)d_in[16];
  const float* ro_gate_w=(const float*)d_in[17];
  const float* ro_gate_b=(const float*)d_in[18];
  const float* ro_lin2_w=(const float*)d_in[19];
  const float* glin_w0=(const float*)d_in[20];
  const float* glin_b0=(const float*)d_in[21];
  const float* glin_w2=(const float*)d_in[22];
  const float* prod_pw2=(const float*)d_in[23];
  const float* prod_pw3=(const float*)d_in[24];
  const float* prod_lin=(const float*)d_in[25];
  const float* fo_w=(const float*)d_in[26];
  const int* edge_index=(const int*)d_in[27];
  const int* batch=(const int*)d_in[28];
  const int N=in_sizes[1];
  const int E=in_sizes[2];
  const int G=128;
  float* out=(float*)d_out;

  // ---- workspace layout (floats); sort bufs; Tbl last, optional ----
  float* p=(float*)d_ws;
  float* shb=p;    p+=(size_t)12*E;
  float* efb=p;    p+=(size_t)12*E;
  float* bufA=p;   p+=(size_t)N*576;
  float* bufB=p;   p+=(size_t)N*576;
  float* gatesb=p; p+=(size_t)N*128;
  float* M123=p;   p+=3*4096;
  float* Svec=p;   p+=64;
  float* Tvec=p;   p+=64;
  float* bias2=p;  p+=64;
  float* m2T1=p;   p+=16384;
  float* m2T2=p;   p+=49152;
  float* gsum=p;   p+=(size_t)G*576;
  float* cntb=p;   p+=G;
  int* offs=(int*)p;   p+=N;
  int* posOf=(int*)p;  p+=E;
  int* sndS=(int*)p;   p+=E;
  int* rcvS=(int*)p;   p+=E;
  size_t baseNeed=(size_t)(p-(float*)d_ws)*sizeof(float);
  if(baseNeed>ws_size) return;
  float* Tbl=p;
  bool useTbl = (baseNeed + (size_t)96*E*sizeof(float)) <= ws_size;
  if(!useTbl) Tbl=nullptr;

  // ---- constant Wigner-3j tables ----
  WAll wa; Wg wg;
  {
    float t000[1],t011[9],t022[25],t101[9],t110[9],t112[45],t121[45],t202[25],t211[45],t220[25],t222[125],t224[225];
    real_w3j(0,0,0,t000); real_w3j(0,1,1,t011); real_w3j(0,2,2,t022);
    real_w3j(1,0,1,t101); real_w3j(1,1,0,t110); real_w3j(1,1,2,t112); real_w3j(1,2,1,t121);
    real_w3j(2,0,2,t202); real_w3j(2,1,1,t211); real_w3j(2,2,0,t220); real_w3j(2,2,2,t222); real_w3j(2,2,4,t224);
    wa.w000=t000[0];
    std::memcpy(wa.w011,t011,sizeof t011); std::memcpy(wa.w022,t022,sizeof t022);
    std::memcpy(wa.w101,t101,sizeof t101); std::memcpy(wa.w110,t110,sizeof t110);
    std::memcpy(wa.w112,t112,sizeof t112); std::memcpy(wa.w121,t121,sizeof t121);
    std::memcpy(wa.w202,t202,sizeof t202); std::memcpy(wa.w211,t211,sizeof t211);
    std::memcpy(wa.w220,t220,sizeof t220); std::memcpy(wa.w222,t222,sizeof t222);
    wg.w000=t000[0];
    std::memcpy(wg.w022,t022,sizeof t022); std::memcpy(wg.w202,t202,sizeof t202);
    std::memcpy(wg.w220,t220,sizeof t220); std::memcpy(wg.w222,t222,sizeof t222);
    std::memcpy(wg.w224,t224,sizeof t224);
  }

  // ---- pipeline ----
  k_prep<<<49,256,0,stream>>>(W_embed,b_embed,up1_w,lin1_w,lin1_b,up2_w,M123,Svec,Tvec,bias2);
  k_shuf<<<256,256,0,stream>>>(mlp1_w2,mlp2_w2,m2T1,m2T2);

  // counting sort of edges by receiver (in-place parallel scan, no memcpy)
  hipMemsetAsync(offs,0,(size_t)N*sizeof(int),stream);
  k_hist<<<(E+255)/256,256,0,stream>>>(edge_index,offs,E);
  k_scan<<<1,256,0,stream>>>(offs,N);
  k_scatter<<<(E+255)/256,256,0,stream>>>(edge_index,offs,posOf,sndS,rcvS,E);

  k_geom<<<(E+255)/256,256,0,stream>>>(positions,shifts,edge_attr,edge_index,posOf,shb,efb,Tbl,E,wa);

  hipMemsetAsync(bufA,0,(size_t)N*576*sizeof(float),stream);
  const int eblocks=1280;
  if(useTbl)
    k_edge1<1><<<eblocks,256,0,stream>>>(node_attrs,Svec,Tvec,mlp1_w1,m2T1,shb,Tbl,efb,sndS,rcvS,bufA,E,wa);
  else
    k_edge1<0><<<eblocks,256,0,stream>>>(node_attrs,Svec,Tvec,mlp1_w1,m2T1,shb,Tbl,efb,sndS,rcvS,bufA,E,wa);

  dim3 ngrid((N+15)/16,9);
  k_node<0><<<ngrid,256,0,stream>>>(bufA,bufB,M123,bias2,nullptr,nullptr,N,1.0f);       // agg1 -> ups2

  hipMemsetAsync(bufA,0,(size_t)N*576*sizeof(float),stream);
  if(useTbl)
    k_edge2<1><<<eblocks,256,0,stream>>>(bufB,mlp2_w1,m2T2,shb,Tbl,efb,sndS,rcvS,bufA,E,wa);
  else
    k_edge2<0><<<eblocks,256,0,stream>>>(bufB,mlp2_w1,m2T2,shb,Tbl,efb,sndS,rcvS,bufA,E,wa);

  // fused: agg2 -> xs -> gates -> y   (in-place on bufA)
  k_node_fused<<<(N+15)/16,256,0,stream>>>(bufA,bufA,lin2_w,lin2_b,ro_gate_w,ro_gate_b,ro_lin_w,N);

  hipMemsetAsync(gsum,0,((size_t)G*576+G)*sizeof(float),stream);
  k_cnt<<<(N+255)/256,256,0,stream>>>(batch,cntb,N);
  k_node<3><<<ngrid,256,0,stream>>>(bufA,gsum,ro_lin2_w,nullptr,nullptr,batch,N,1.0f);  // y -> gsum

  k_graph<<<G,256,0,stream>>>(gsum,cntb,glin_w0,glin_b0,glin_w2,prod_pw2,prod_pw3,prod_lin,fo_w,out,wg);
}

// Round 21
// 1289.253 us; speedup vs baseline: 1.2445x; 1.2445x over previous
//
#include <hip/hip_runtime.h>
#include <cmath>
#include <complex>
#include <vector>
#include <cstring>

// ============================ host: Wigner-3j tables ============================
static double hfact(int n){ double r=1; for(int i=2;i<=n;i++) r*=i; return r; }

static double hcg(int l1,int m1,int l2,int m2,int l3,int m3){
  if(m3!=m1+m2) return 0.0;
  double pre = std::sqrt((2*l3+1)*hfact(l3+l1-l2)*hfact(l3-l1+l2)*hfact(l1+l2-l3)/hfact(l1+l2+l3+1));
  pre *= std::sqrt(hfact(l3+m3)*hfact(l3-m3)*hfact(l1-m1)*hfact(l1+m1)*hfact(l2-m2)*hfact(l2+m2));
  double s=0;
  for(int k=0;k<=l1+l2-l3;k++){
    int d0=k,d1=l1+l2-l3-k,d2=l1-m1-k,d3=l2+m2-k,d4=l3-l2+m1+k,d5=l3-l1-m2+k;
    if(d0<0||d1<0||d2<0||d3<0||d4<0||d5<0) continue;
    double den=hfact(d0)*hfact(d1)*hfact(d2)*hfact(d3)*hfact(d4)*hfact(d5);
    s += ((k&1)?-1.0:1.0)/den;
  }
  return pre*s;
}

static void hU(int l, std::complex<double>* U){
  int n=2*l+1;
  for(int i=0;i<n*n;i++) U[i]=std::complex<double>(0.0,0.0);
  U[l*n+l]=1.0;
  double s2=std::sqrt(0.5);
  for(int m=1;m<=l;m++){
    double sgn=(m&1)?-1.0:1.0;
    U[(l+m)*n+(l+m)] = sgn*s2;
    U[(l+m)*n+(l-m)] = s2;
    U[(l-m)*n+(l-m)] = std::complex<double>(0.0, s2);
    U[(l-m)*n+(l+m)] = std::complex<double>(0.0, -sgn*s2);
  }
}

static void real_w3j(int l1,int l2,int l3, float* out){
  int n1=2*l1+1,n2=2*l2+1,n3=2*l3+1;
  std::vector<double> w((size_t)n1*n2*n3,0.0);
  for(int m1=-l1;m1<=l1;m1++)for(int m2=-l2;m2<=l2;m2++){
    int m3=-(m1+m2);
    if(m3<-l3||m3>l3) continue;
    int e=l1-l2-m3;
    double sgn = (((e%2)+2)%2)?-1.0:1.0;
    w[((size_t)(m1+l1)*n2+(m2+l2))*n3+(m3+l3)] = sgn*hcg(l1,m1,l2,m2,l3,-m3)/std::sqrt((double)(2*l3+1));
  }
  std::vector<std::complex<double>> U1((size_t)n1*n1),U2((size_t)n2*n2),U3((size_t)n3*n3),R((size_t)n1*n2*n3,std::complex<double>(0,0));
  hU(l1,U1.data()); hU(l2,U2.data()); hU(l3,U3.data());
  for(int i=0;i<n1;i++)for(int j=0;j<n2;j++)for(int k=0;k<n3;k++){
    std::complex<double> acc(0.0,0.0);
    for(int m=0;m<n1;m++){
      std::complex<double> u1=U1[i*n1+m]; if(u1.real()==0.0&&u1.imag()==0.0) continue;
      for(int nn=0;nn<n2;nn++){
        std::complex<double> u2=U2[j*n2+nn]; if(u2.real()==0.0&&u2.imag()==0.0) continue;
        std::complex<double> u12=u1*u2;
        for(int o=0;o<n3;o++){
          double wv=w[((size_t)m*n2+nn)*n3+o];
          if(wv!=0.0) acc += u12*U3[k*n3+o]*wv;
        }
      }
    }
    R[((size_t)i*n2+j)*n3+k]=acc;
  }
  double mre=0,mim=0;
  for(size_t t=0;t<R.size();t++){ mre=std::max(mre,std::fabs(R[t].real())); mim=std::max(mim,std::fabs(R[t].imag())); }
  bool useRe = (mre>=mim);
  double nrm=0;
  for(size_t t=0;t<R.size();t++){ double v=useRe?R[t].real():R[t].imag(); nrm+=v*v; }
  nrm=std::sqrt(nrm);
  for(size_t t=0;t<R.size();t++){ double v=useRe?R[t].real():R[t].imag(); out[t]=(float)(v/nrm); }
}

// All 11 interaction-path W3J tables (kernarg). (0,l,l)/(l,0,l)/(l,l,0) are diagonal.
struct WAll {
  float w000;
  float w011[9];
  float w022[25];
  float w101[9];
  float w110[9];
  float w112[45];
  float w121[45];
  float w202[25];
  float w211[45];
  float w220[25];
  float w222[125];
};
struct Wg { float w000; float w022[25]; float w202[25]; float w220[25]; float w222[125]; float w224[225]; };

// ============================ device helpers ============================
__device__ __forceinline__ float bcast(float v, int l){
  return __int_as_float(__builtin_amdgcn_readlane(__float_as_int(v), l));
}
__device__ __forceinline__ float silu(float x){ return x/(1.f+expf(-x)); }

// ============================ k_prep ============================
__global__ __launch_bounds__(256) void k_prep(
  const float* __restrict__ We, const float* __restrict__ be, const float* __restrict__ up1,
  const float* __restrict__ lin1, const float* __restrict__ lin1b, const float* __restrict__ up2,
  float* __restrict__ M123, float* __restrict__ Svec, float* __restrict__ Tvec, float* __restrict__ bias2)
{
  int idx=blockIdx.x*256+threadIdx.x;
  if(idx<12288){
    int l=idx>>12, c=(idx>>6)&63, d=idx&63;
    float a=0;
    for(int k=0;k<64;k++) a+=lin1[l*4096+c*64+k]*up2[l*4096+k*64+d];
    M123[idx]=0.1f*a;
  } else if(idx<12352){
    int d=idx-12288; float a=0;
    for(int c=0;c<64;c++) a+=We[c]*up1[c*64+d];
    Svec[d]=a;
  } else if(idx<12416){
    int d=idx-12352; float a=0;
    for(int c=0;c<64;c++) a+=be[c]*up1[c*64+d];
    Tvec[d]=a;
  } else if(idx<12480){
    int d=idx-12416; float a=0;
    for(int c=0;c<64;c++) a+=lin1b[c]*up2[c*64+d];
    bias2[d]=a;
  }
}

// k_shuf: T1 [(h*64+c)*4+p] ; T2 quad-planes [((h*3+q)*64+c)*4+j] = w[h][(4q+j)*64+c]
__global__ __launch_bounds__(256) void k_shuf(
  const float* __restrict__ w2a, const float* __restrict__ w2b,
  float* __restrict__ T1, float* __restrict__ T2)
{
  int idx=blockIdx.x*256+threadIdx.x;
  if(idx<16384){
    int p=idx&3, c=(idx>>2)&63, h=idx>>8;
    T1[idx]=(p<3)? w2a[h*192+p*64+c] : 0.f;
  } else if(idx<16384+49152){
    int q2=idx-16384;
    int h=q2/768, rem=q2%768, qq=rem>>8, rem2=rem&255, c=rem2>>2, j=rem2&3;
    int p=qq*4+j;
    T2[q2]=(p<11)? w2b[h*704+p*64+c] : 0.f;
  }
}

// ============================ counting sort by receiver ============================
__global__ __launch_bounds__(256) void k_hist(const int* __restrict__ eidx, int* __restrict__ hist, int E){
  int e=blockIdx.x*256+threadIdx.x;
  if(e<E) atomicAdd(&hist[eidx[E+e]], 1);
}

// in-place exclusive scan: 256 threads, chunk-per-thread, one LDS scan of totals
__global__ __launch_bounds__(256) void k_scan(int* __restrict__ ho, int N){
  __shared__ int tsum[256];
  int tid=threadIdx.x;
  int chunk=(N+255)/256;
  int lo=tid*chunk; if(lo>N) lo=N;
  int hi=lo+chunk; if(hi>N) hi=N;
  int s=0;
  for(int i=lo;i<hi;i++) s+=ho[i];
  tsum[tid]=s;
  __syncthreads();
  for(int off=1;off<256;off<<=1){
    int add=(tid>=off)? tsum[tid-off]:0;
    __syncthreads();
    tsum[tid]+=add;
    __syncthreads();
  }
  int base=(tid==0)?0:tsum[tid-1];
  for(int i=lo;i<hi;i++){
    int v=ho[i];
    ho[i]=base;
    base+=v;
  }
}

__global__ __launch_bounds__(256) void k_scatter(
  const int* __restrict__ eidx, int* __restrict__ offs,
  int* __restrict__ posOf, int* __restrict__ sndS, int* __restrict__ rcvS, int E)
{
  int e=blockIdx.x*256+threadIdx.x;
  if(e<E){
    int r=eidx[E+e];
    int pos=atomicAdd(&offs[r],1);
    posOf[e]=pos;
    sndS[pos]=eidx[e];
    rcvS[pos]=r;
  }
}

// ============================ k_geom (writes receiver-sorted slots) ============
__global__ __launch_bounds__(256) void k_geom(
  const float* __restrict__ pos, const float* __restrict__ shifts,
  const float* __restrict__ eattr, const int* __restrict__ eidx,
  const int* __restrict__ posOf,
  float* __restrict__ shb, float* __restrict__ efb, float* __restrict__ Tbl,
  int E, WAll W)
{
  int e=blockIdx.x*256+threadIdx.x;
  if(e>=E) return;
  int s=eidx[e], r=eidx[E+e];
  int ps=posOf[e];
  float vx=pos[r*3+0]-pos[s*3+0]+shifts[e*3+0];
  float vy=pos[r*3+1]-pos[s*3+1]+shifts[e*3+1];
  float vz=pos[r*3+2]-pos[s*3+2]+shifts[e*3+2];
  float len=sqrtf(vx*vx+vy*vy+vz*vz);
  float inv=1.f/(len+1e-9f);
  float x=vx*inv,y=vy*inv,z=vz*inv;
  const float c3=1.7320508075688772f, c15=3.872983346207417f, c5h=1.118033988749895f, c15h=1.9364916731037085f;
  float s1[3]={c3*x, c3*y, c3*z};
  float s2[5]={c15*x*y, c15*y*z, c5h*(3.f*z*z-1.f), c15*x*z, c15h*(x*x-y*y)};
  float* sp=&shb[(size_t)ps*12];
  sp[0]=1.f; sp[1]=s1[0]; sp[2]=s1[1]; sp[3]=s1[2];
  sp[4]=s2[0]; sp[5]=s2[1]; sp[6]=s2[2]; sp[7]=s2[3]; sp[8]=s2[4];
  sp[9]=0.f; sp[10]=0.f; sp[11]=0.f;
  float ea=eattr[e];
  float* fp=&efb[(size_t)ps*12];
  #pragma unroll
  for(int i=0;i<6;i++){ float d=(len-0.12f*(float)i)/0.12f; fp[i]=expf(-d*d)/1.12f; }
  #pragma unroll
  for(int i=0;i<6;i++){ float d=(ea-0.006f*(float)i)/0.006f; fp[6+i]=expf(-d*d)/1.12f; }
  if(Tbl){
    float* tb=&Tbl[(size_t)ps*96];
    #pragma unroll
    for(int k=0;k<3;k++) tb[k]=s1[k]*W.w011[k*4];
    tb[3]=0.f;
    #pragma unroll
    for(int k=0;k<5;k++) tb[4+k]=s2[k]*W.w022[k*6];
    tb[9]=0.f; tb[10]=0.f; tb[11]=0.f;
    #pragma unroll
    for(int i=0;i<3;i++) tb[12+i]=s1[i]*W.w110[i*4];
    tb[15]=0.f;
    #pragma unroll
    for(int i=0;i<5;i++) tb[16+i]=s2[i]*W.w220[i*6];
    tb[21]=0.f; tb[22]=0.f; tb[23]=0.f;
    #pragma unroll
    for(int i=0;i<3;i++)
      #pragma unroll
      for(int k=0;k<3;k++){ float t=0;
        #pragma unroll
        for(int j=0;j<5;j++) t+=s2[j]*W.w121[(i*5+j)*3+k];
        tb[24+i*3+k]=t; }
    tb[33]=0.f; tb[34]=0.f; tb[35]=0.f;
    #pragma unroll
    for(int i=0;i<5;i++)
      #pragma unroll
      for(int k=0;k<3;k++){ float t=0;
        #pragma unroll
        for(int j=0;j<3;j++) t+=s1[j]*W.w211[(i*3+j)*3+k];
        tb[36+i*3+k]=t; }
    tb[51]=0.f;
    #pragma unroll
    for(int i=0;i<3;i++)
      #pragma unroll
      for(int k=0;k<5;k++){ float t=0;
        #pragma unroll
        for(int j=0;j<3;j++) t+=s1[j]*W.w112[(i*3+j)*5+k];
        tb[52+i*5+k]=t; }
    tb[67]=0.f;
    #pragma unroll
    for(int i=0;i<5;i++)
      #pragma unroll
      for(int k=0;k<5;k++){ float t=0;
        #pragma unroll
        for(int j=0;j<5;j++) t+=s2[j]*W.w222[(i*5+j)*5+k];
        tb[68+i*5+k]=t; }
    tb[93]=0.f; tb[94]=0.f; tb[95]=0.f;
  }
}

// ============================ k_edge1: chunked-LDS b128, sorted + run-merged ============
template<int TBL>
__global__ __launch_bounds__(256) void k_edge1(
  const float* __restrict__ na, const float* __restrict__ SV, const float* __restrict__ TV,
  const float* __restrict__ m1, const float* __restrict__ m2T,
  const float* __restrict__ sh, const float* __restrict__ Tbl, const float* __restrict__ ef,
  const int* __restrict__ sndS, const int* __restrict__ rcvS,
  float* __restrict__ agg, int E, WAll W)
{
  __shared__ __align__(16) float wl[8*256];
  __shared__ float m1s[768];
  int tid=threadIdx.x, lane=tid&63, wid=tid>>6;
  for(int i=tid;i<768;i+=256) m1s[i]=m1[i];
  float Sv=SV[lane], Tv=TV[lane];
  __syncthreads();
  int nb=(E+31)/32;
  for(int b=blockIdx.x;b<nb;b+=gridDim.x){
    int e0=b*32+wid*8;
    float hid[8]; float acc[8][3];
    #pragma unroll
    for(int e=0;e<8;e++){
      float h=0.f;
      if(e0+e<E){
        const float4* fp=(const float4*)(ef+(size_t)(e0+e)*12);
        float4 f0=fp[0], f1=fp[1], f2=fp[2];
        h = f0.x*m1s[0*64+lane]+f0.y*m1s[1*64+lane]+f0.z*m1s[2*64+lane]+f0.w*m1s[3*64+lane]
          + f1.x*m1s[4*64+lane]+f1.y*m1s[5*64+lane]+f1.z*m1s[6*64+lane]+f1.w*m1s[7*64+lane]
          + f2.x*m1s[8*64+lane]+f2.y*m1s[9*64+lane]+f2.z*m1s[10*64+lane]+f2.w*m1s[11*64+lane];
      }
      hid[e]=silu(h);
      acc[e][0]=0; acc[e][1]=0; acc[e][2]=0;
    }
    for(int ch=0;ch<8;ch++){
      __syncthreads();
      const float4* src=(const float4*)(m2T+(size_t)ch*2048);
      float4* dst4=(float4*)wl;
      dst4[tid]=src[tid];
      dst4[tid+256]=src[tid+256];
      __syncthreads();
      #pragma unroll
      for(int h8=0;h8<8;h8++){
        int h=ch*8+h8;
        float4 mv=*(const float4*)&wl[(h8*64+lane)*4];
        #pragma unroll
        for(int e=0;e<8;e++){
          float s=bcast(hid[e],h);
          acc[e][0]+=s*mv.x; acc[e][1]+=s*mv.y; acc[e][2]+=s*mv.z;
        }
      }
    }
    // run-merged epilogue (rcvS non-decreasing)
    float carry[9];
    #pragma unroll
    for(int k=0;k<9;k++) carry[k]=0.f;
    int lastR=-1;
    #pragma unroll
    for(int e=0;e<8;e++){
      int ee=e0+e;
      if(ee>=E) break;
      int snd=sndS[ee], rcv=rcvS[ee];
      if(lastR>=0 && rcv!=lastR){
        float* dst=&agg[(size_t)lastR*576];
        atomicAdd(&dst[lane], carry[0]);
        #pragma unroll
        for(int k=0;k<3;k++) atomicAdd(&dst[(1+k)*64+lane], carry[1+k]);
        #pragma unroll
        for(int k=0;k<5;k++) atomicAdd(&dst[(4+k)*64+lane], carry[4+k]);
        #pragma unroll
        for(int k=0;k<9;k++) carry[k]=0.f;
      }
      float g0 = na[snd]*Sv + Tv;
      if constexpr(TBL){
        const float* tb=&Tbl[(size_t)ee*96];
        carry[0]+=g0*W.w000*acc[e][0];
        #pragma unroll
        for(int k=0;k<3;k++) carry[1+k]+=g0*acc[e][1]*tb[k];
        #pragma unroll
        for(int k=0;k<5;k++) carry[4+k]+=g0*acc[e][2]*tb[4+k];
      } else {
        const float4* shp=(const float4*)(sh+(size_t)ee*12);
        float4 h0=shp[0], h1=shp[1], h2=shp[2];
        float s1[3]={h0.y,h0.z,h0.w};
        float s2[5]={h1.x,h1.y,h1.z,h1.w,h2.x};
        carry[0]+=g0*W.w000*acc[e][0];
        #pragma unroll
        for(int k=0;k<3;k++) carry[1+k]+=g0*acc[e][1]*s1[k]*W.w011[k*4];
        #pragma unroll
        for(int k=0;k<5;k++) carry[4+k]+=g0*acc[e][2]*s2[k]*W.w022[k*6];
      }
      lastR=rcv;
    }
    if(lastR>=0){
      float* dst=&agg[(size_t)lastR*576];
      atomicAdd(&dst[lane], carry[0]);
      #pragma unroll
      for(int k=0;k<3;k++) atomicAdd(&dst[(1+k)*64+lane], carry[1+k]);
      #pragma unroll
      for(int k=0;k<5;k++) atomicAdd(&dst[(4+k)*64+lane], carry[4+k]);
    }
  }
}

// ============================ k_edge2: chunked-LDS quad-plane, sorted + run-merged ====
template<int TBL>
__global__ __launch_bounds__(256) void k_edge2(
  const float* __restrict__ ups2, const float* __restrict__ m1, const float* __restrict__ m2T,
  const float* __restrict__ sh, const float* __restrict__ Tbl, const float* __restrict__ ef,
  const int* __restrict__ sndS, const int* __restrict__ rcvS,
  float* __restrict__ agg, int E, WAll W)
{
  __shared__ __align__(16) float wl[8*768];
  __shared__ float m1s[768];
  int tid=threadIdx.x, lane=tid&63, wid=tid>>6;
  for(int i=tid;i<768;i+=256) m1s[i]=m1[i];
  __syncthreads();
  int nb=(E+15)/16;
  for(int b=blockIdx.x;b<nb;b+=gridDim.x){
    int e0=b*16+wid*4;
    float hid[4]; float acc[4][11];
    #pragma unroll
    for(int e=0;e<4;e++){
      float h=0.f;
      if(e0+e<E){
        const float4* fp=(const float4*)(ef+(size_t)(e0+e)*12);
        float4 f0=fp[0], f1=fp[1], f2=fp[2];
        h = f0.x*m1s[0*64+lane]+f0.y*m1s[1*64+lane]+f0.z*m1s[2*64+lane]+f0.w*m1s[3*64+lane]
          + f1.x*m1s[4*64+lane]+f1.y*m1s[5*64+lane]+f1.z*m1s[6*64+lane]+f1.w*m1s[7*64+lane]
          + f2.x*m1s[8*64+lane]+f2.y*m1s[9*64+lane]+f2.z*m1s[10*64+lane]+f2.w*m1s[11*64+lane];
      }
      hid[e]=silu(h);
      #pragma unroll
      for(int p=0;p<11;p++) acc[e][p]=0.f;
    }
    for(int ch=0;ch<8;ch++){
      __syncthreads();
      const float4* src=(const float4*)(m2T+(size_t)ch*6144);
      float4* dst4=(float4*)wl;
      #pragma unroll
      for(int i=0;i<6;i++) dst4[tid+i*256]=src[tid+i*256];
      __syncthreads();
      #pragma unroll
      for(int h8=0;h8<8;h8++){
        int h=ch*8+h8;
        float4 q0=*(const float4*)&wl[((h8*3+0)*64+lane)*4];
        float4 q1=*(const float4*)&wl[((h8*3+1)*64+lane)*4];
        float4 q2=*(const float4*)&wl[((h8*3+2)*64+lane)*4];
        #pragma unroll
        for(int e=0;e<4;e++){
          float s=bcast(hid[e],h);
          acc[e][0]+=s*q0.x; acc[e][1]+=s*q0.y; acc[e][2]+=s*q0.z; acc[e][3]+=s*q0.w;
          acc[e][4]+=s*q1.x; acc[e][5]+=s*q1.y; acc[e][6]+=s*q1.z; acc[e][7]+=s*q1.w;
          acc[e][8]+=s*q2.x; acc[e][9]+=s*q2.y; acc[e][10]+=s*q2.z;
        }
      }
    }
    // run-merged epilogue (rcvS non-decreasing)
    float carry[9];
    #pragma unroll
    for(int k=0;k<9;k++) carry[k]=0.f;
    int lastR=-1;
    #pragma unroll
    for(int e=0;e<4;e++){
      int ee=e0+e;
      if(ee>=E) break;
      int snd=sndS[ee], rcv=rcvS[ee];
      if(lastR>=0 && rcv!=lastR){
        float* dst=&agg[(size_t)lastR*576];
        atomicAdd(&dst[lane], carry[0]);
        #pragma unroll
        for(int k=0;k<3;k++) atomicAdd(&dst[(1+k)*64+lane], carry[1+k]);
        #pragma unroll
        for(int k=0;k<5;k++) atomicAdd(&dst[(4+k)*64+lane], carry[4+k]);
        #pragma unroll
        for(int k=0;k<9;k++) carry[k]=0.f;
      }
      const float* up=&ups2[(size_t)snd*576];
      float a0=acc[e][0],a1=acc[e][1],a2=acc[e][2],a3=acc[e][3];
      float a4=acc[e][4],a5=acc[e][5],a6=acc[e][6],a7=acc[e][7];
      float a8=acc[e][8],a9=acc[e][9],a10=acc[e][10];
      float g0=up[lane];
      float g1[3], g2[5];
      #pragma unroll
      for(int i=0;i<3;i++) g1[i]=up[(1+i)*64+lane];
      #pragma unroll
      for(int i=0;i<5;i++) g2[i]=up[(4+i)*64+lane];
      if constexpr(TBL){
        const float* tb=&Tbl[(size_t)ee*96];
        {
          float t110 = g1[0]*tb[12]+g1[1]*tb[13]+g1[2]*tb[14];
          float t220 = g2[0]*tb[16]+g2[1]*tb[17]+g2[2]*tb[18]+g2[3]*tb[19]+g2[4]*tb[20];
          carry[0] += W.w000*g0*a0 + a4*t110 + a9*t220;
        }
        #pragma unroll
        for(int k=0;k<3;k++){
          float t121 = g1[0]*tb[24+k]+g1[1]*tb[27+k]+g1[2]*tb[30+k];
          float t211 = g2[0]*tb[36+k]+g2[1]*tb[39+k]+g2[2]*tb[42+k]+g2[3]*tb[45+k]+g2[4]*tb[48+k];
          carry[1+k] += g0*a1*tb[k] + a3*g1[k]*W.w101[k*4] + a6*t121 + a8*t211;
        }
        #pragma unroll
        for(int k=0;k<5;k++){
          float t112 = g1[0]*tb[52+k]+g1[1]*tb[57+k]+g1[2]*tb[62+k];
          float t222 = g2[0]*tb[68+k]+g2[1]*tb[73+k]+g2[2]*tb[78+k]+g2[3]*tb[83+k]+g2[4]*tb[88+k];
          carry[4+k] += g0*a2*tb[4+k] + a7*g2[k]*W.w202[k*6] + a5*t112 + a10*t222;
        }
      } else {
        const float4* shp=(const float4*)(sh+(size_t)ee*12);
        float4 h0=shp[0], h1=shp[1], h2=shp[2];
        float s1[3]={h0.y,h0.z,h0.w};
        float s2[5]={h1.x,h1.y,h1.z,h1.w,h2.x};
        {
          float t110 = g1[0]*s1[0]*W.w110[0]+g1[1]*s1[1]*W.w110[4]+g1[2]*s1[2]*W.w110[8];
          float t220 = 0;
          #pragma unroll
          for(int i=0;i<5;i++) t220 += g2[i]*s2[i]*W.w220[i*6];
          carry[0] += W.w000*g0*a0 + a4*t110 + a9*t220;
        }
        #pragma unroll
        for(int k=0;k<3;k++){
          float mk = g0*a1*s1[k]*W.w011[k*4];
          mk += a3*g1[k]*W.w101[k*4];
          float t=0;
          #pragma unroll
          for(int i=0;i<3;i++){ float u=0;
            #pragma unroll
            for(int j=0;j<5;j++) u+=s2[j]*W.w121[(i*5+j)*3+k];
            t+=g1[i]*u; }
          mk += a6*t;
          t=0;
          #pragma unroll
          for(int i=0;i<5;i++){ float u=0;
            #pragma unroll
            for(int j=0;j<3;j++) u+=s1[j]*W.w211[(i*3+j)*3+k];
            t+=g2[i]*u; }
          mk += a8*t;
          carry[1+k]+=mk;
        }
        #pragma unroll
        for(int k=0;k<5;k++){
          float mk = g0*a2*s2[k]*W.w022[k*6];
          float t=0;
          #pragma unroll
          for(int i=0;i<3;i++){ float u=0;
            #pragma unroll
            for(int j=0;j<3;j++) u+=s1[j]*W.w112[(i*3+j)*5+k];
            t+=g1[i]*u; }
          mk += a5*t;
          mk += a7*g2[k]*W.w202[k*6];
          t=0;
          #pragma unroll
          for(int i=0;i<5;i++){ float u=0;
            #pragma unroll
            for(int j=0;j<5;j++) u+=s2[j]*W.w222[(i*5+j)*5+k];
            t+=g2[i]*u; }
          mk += a10*t;
          carry[4+k]+=mk;
        }
      }
      lastR=rcv;
    }
    if(lastR>=0){
      float* dst=&agg[(size_t)lastR*576];
      atomicAdd(&dst[lane], carry[0]);
      #pragma unroll
      for(int k=0;k<3;k++) atomicAdd(&dst[(1+k)*64+lane], carry[1+k]);
      #pragma unroll
      for(int k=0;k<5;k++) atomicAdd(&dst[(4+k)*64+lane], carry[4+k]);
    }
  }
}

// ============================ k_node<MODE> ============================
template<int MODE>
__global__ __launch_bounds__(256) void k_node(
  const float* __restrict__ X, float* __restrict__ Y,
  const float* __restrict__ Ms, const float* __restrict__ bias,
  const float* __restrict__ gates, const int* __restrict__ batch,
  int N, float scale)
{
  int kk=blockIdx.y;
  int l=(kk==0)?0:(kk<4)?1:2;
  __shared__ float Mt[64][68];
  const float* M=Ms+l*4096;
  int tid=threadIdx.x;
  for(int idx=tid;idx<4096;idx+=256){ int c=idx>>6,d=idx&63; Mt[d][c]=M[idx]; }
  __syncthreads();
  int lane=tid&63, wid=tid>>6;
  int n0=(blockIdx.x*4+wid)*4;
  float xr[4];
  #pragma unroll
  for(int t=0;t<4;t++){ int n=n0+t; xr[t]=(n<N)?X[(size_t)n*576+kk*64+lane]:0.f; }
  float acc[4]={0,0,0,0};
  for(int cb=0;cb<64;cb+=4){
    float4 mv=*(const float4*)&Mt[lane][cb];
    #pragma unroll
    for(int t=0;t<4;t++){
      acc[t]+=bcast(xr[t],cb+0)*mv.x;
      acc[t]+=bcast(xr[t],cb+1)*mv.y;
      acc[t]+=bcast(xr[t],cb+2)*mv.z;
      acc[t]+=bcast(xr[t],cb+3)*mv.w;
    }
  }
  #pragma unroll
  for(int t=0;t<4;t++){
    int n=n0+t; if(n>=N) break;
    float v=acc[t]*scale;
    if constexpr(MODE==0||MODE==1){
      if(kk==0) v+=bias[lane];
      Y[(size_t)n*576+kk*64+lane]=v;
    } else if constexpr(MODE==2){
      if(kk==0) v=silu(v);
      else if(kk<4) v*=gates[(size_t)n*128+lane];
      else v*=gates[(size_t)n*128+64+lane];
      Y[(size_t)n*576+kk*64+lane]=v;
    } else {
      int bg=batch[n];
      atomicAdd(&Y[(size_t)bg*576+kk*64+lane], v);
    }
  }
}

// ============================ k_gates ============================
__global__ __launch_bounds__(256) void k_gates(
  const float* __restrict__ xs, const float* __restrict__ gw, const float* __restrict__ gb,
  float* __restrict__ gates, int N)
{
  __shared__ float Gt[128][68];
  int tid=threadIdx.x;
  for(int idx=tid; idx<8192; idx+=256){ int c=idx>>7, t=idx&127; Gt[t][c]=gw[c*128+t]; }
  __syncthreads();
  int lane=tid&63, wid=tid>>6;
  int n0=(blockIdx.x*4+wid)*4;
  float xr[4];
  #pragma unroll
  for(int t=0;t<4;t++){ int n=n0+t; xr[t]=(n<N)?xs[(size_t)n*576+lane]:0.f; }
  float a0[4]={0,0,0,0}, a1[4]={0,0,0,0};
  for(int cb=0;cb<64;cb+=4){
    float4 m0=*(const float4*)&Gt[lane][cb];
    float4 m1=*(const float4*)&Gt[64+lane][cb];
    #pragma unroll
    for(int t=0;t<4;t++){
      float x0=bcast(xr[t],cb), x1=bcast(xr[t],cb+1), x2=bcast(xr[t],cb+2), x3=bcast(xr[t],cb+3);
      a0[t]+=x0*m0.x+x1*m0.y+x2*m0.z+x3*m0.w;
      a1[t]+=x0*m1.x+x1*m1.y+x2*m1.z+x3*m1.w;
    }
  }
  #pragma unroll
  for(int t=0;t<4;t++){
    int n=n0+t; if(n>=N) break;
    float g0=a0[t]+gb[lane], g1=a1[t]+gb[64+lane];
    gates[(size_t)n*128+lane]=silu(g0);
    gates[(size_t)n*128+64+lane]=silu(g1);
  }
}

// ============================ k_cnt ============================
__global__ __launch_bounds__(256) void k_cnt(const int* __restrict__ batch, float* __restrict__ cnt, int N){
  int n=blockIdx.x*256+threadIdx.x;
  if(n<N) atomicAdd(&cnt[batch[n]], 1.f);
}

// ============================ k_graph ============================
__device__ void ctp_dev(const float* a0, const float* a2, const float* b0, const float* b2,
                        const float* pw, float* o0, float* o2, int c, const Wg& W)
{
  float A0=a0[c], B0=b0[c], A2[5], B2[5];
  #pragma unroll
  for(int i=0;i<5;i++){ A2[i]=a2[c*5+i]; B2[i]=b2[c*5+i]; }
  float o = pw[0*16+c]*A0*B0*W.w000;
  { float t=0;
    #pragma unroll
    for(int i=0;i<5;i++)
      #pragma unroll
      for(int j=0;j<5;j++) t+=A2[i]*B2[j]*W.w220[i*5+j];
    o += pw[3*16+c]*t; }
  o0[c]=o;
  #pragma unroll
  for(int k=0;k<5;k++){
    float t=0;
    { float s=0;
      #pragma unroll
      for(int j=0;j<5;j++) s+=B2[j]*W.w022[j*5+k];
      t+=pw[1*16+c]*A0*s; }
    { float s=0;
      #pragma unroll
      for(int i=0;i<5;i++) s+=A2[i]*W.w202[i*5+k];
      t+=pw[2*16+c]*s*B0; }
    { float s=0;
      #pragma unroll
      for(int i=0;i<5;i++)
        #pragma unroll
        for(int j=0;j<5;j++) s+=A2[i]*B2[j]*W.w222[(i*5+j)*5+k];
      t+=pw[4*16+c]*s; }
    o2[c*5+k]=t;
  }
}

__global__ __launch_bounds__(256) void k_graph(
  const float* __restrict__ gsum, const float* __restrict__ cnt,
  const float* __restrict__ glin_w0, const float* __restrict__ glin_b0, const float* __restrict__ glin_w2,
  const float* __restrict__ pw2, const float* __restrict__ pw3, const float* __restrict__ PL,
  const float* __restrict__ fo_w, float* __restrict__ out, Wg W)
{
  int g=blockIdx.x, tid=threadIdx.x;
  __shared__ float g0[64], g2[64*5];
  __shared__ float r0[16], r2[16*5];
  __shared__ float t20[16], t22[16*5];
  __shared__ float t30[16], t32[16*5];
  __shared__ float rp0[16], rp2[16*5];
  __shared__ float outs0[2], outs2[10], outs4[9];
  __shared__ float vv[21], stf[81], Cm[36];
  __shared__ float B21s[21*81];

  if(tid<21){
    const int pi[6]={0,1,2,1,0,0}, pj[6]={0,1,2,2,2,1};
    int a=0,b=0,idx=tid;
    for(a=0;a<6;a++){ int c6=6-a; if(idx<c6){ b=a+idx; break; } idx-=c6; }
    float ma[9]; float mb[9];
    for(int x=0;x<9;x++){ ma[x]=0; mb[x]=0; }
    { float v=(pi[a]==pj[a])?1.f:0.7071067811865476f; ma[pi[a]*3+pj[a]]=v; ma[pj[a]*3+pi[a]]=v; }
    { float v=(pi[b]==pj[b])?1.f:0.7071067811865476f; mb[pi[b]*3+pj[b]]=v; mb[pj[b]*3+pi[b]]=v; }
    float T[81]; float nrm=0;
    for(int x=0;x<81;x++){
      int ij=x/9, kl=x%9;
      float t=0.5f*(ma[ij]*mb[kl]+mb[ij]*ma[kl]);
      T[x]=t; nrm+=t*t;
    }
    nrm=sqrtf(nrm);
    for(int x=0;x<81;x++) B21s[tid*81+x]=T[x]/nrm;
  }

  float cinv=1.f/fmaxf(cnt[g],1.f);
  if(tid<64){
    g0[tid]=gsum[(size_t)g*576+tid]*cinv;
    for(int k=0;k<5;k++) g2[tid*5+k]=gsum[(size_t)g*576+(4+k)*64+tid]*cinv;
  }
  __syncthreads();

  if(tid<16){
    float a=0;
    for(int c=0;c<64;c++) a+=g0[c]*glin_w0[c*16+tid];
    r0[tid]=a+glin_b0[tid];
  } else if(tid<96){
    int u=(tid-16)/5, k=(tid-16)%5; float a=0;
    for(int c=0;c<64;c++) a+=g2[c*5+k]*glin_w2[c*16+u];
    r2[u*5+k]=a;
  }
  __syncthreads();

  if(tid<16) ctp_dev(r0,r2, r0,r2, pw2, t20,t22, tid, W);
  __syncthreads();
  if(tid<16) ctp_dev(t20,t22, r0,r2, pw3, t30,t32, tid, W);
  __syncthreads();

  if(tid<16){
    int d=tid; float a=0;
    for(int c=0;c<16;c++)
      a += r0[c]*PL[(0*2+0)*256+c*16+d] + t20[c]*PL[(1*2+0)*256+c*16+d] + t30[c]*PL[(2*2+0)*256+c*16+d];
    rp0[d]=a;
  } else if(tid<96){
    int q=tid-16, d=q/5, k=q%5; float a=0;
    for(int c=0;c<16;c++)
      a += r2[c*5+k]*PL[(0*2+1)*256+c*16+d] + t22[c*5+k]*PL[(1*2+1)*256+c*16+d] + t32[c*5+k]*PL[(2*2+1)*256+c*16+d];
    rp2[d*5+k]=a;
  }
  if(tid<2) outs0[tid]=0.f;
  else if(tid<12) outs2[tid-2]=0.f;
  else if(tid<21) outs4[tid-12]=0.f;
  __syncthreads();

  {
    int u=tid>>4, v=tid&15;
    float A0=rp0[u], B0=rp0[v], A2[5], B2[5];
    #pragma unroll
    for(int i=0;i<5;i++){ A2[i]=rp2[u*5+i]; B2[i]=rp2[v*5+i]; }
    float s00 = A0*B0*W.w000;
    float s220=0;
    #pragma unroll
    for(int i=0;i<5;i++)
      #pragma unroll
      for(int j=0;j<5;j++) s220+=A2[i]*B2[j]*W.w220[i*5+j];
    float s022[5], s202[5], s222[5], s224[9];
    #pragma unroll
    for(int k=0;k<5;k++){
      float s=0;
      #pragma unroll
      for(int j=0;j<5;j++) s+=B2[j]*W.w022[j*5+k];
      s022[k]=A0*s;
      float s2v=0;
      #pragma unroll
      for(int i=0;i<5;i++) s2v+=A2[i]*W.w202[i*5+k];
      s202[k]=s2v*B0;
      float s3v=0;
      #pragma unroll
      for(int i=0;i<5;i++)
        #pragma unroll
        for(int j=0;j<5;j++) s3v+=A2[i]*B2[j]*W.w222[(i*5+j)*5+k];
      s222[k]=s3v;
    }
    #pragma unroll
    for(int k=0;k<9;k++){
      float s=0;
      #pragma unroll
      for(int i=0;i<5;i++)
        #pragma unroll
        for(int j=0;j<5;j++) s+=A2[i]*B2[j]*W.w224[(i*5+j)*9+k];
      s224[k]=s;
    }
    #pragma unroll
    for(int w=0;w<2;w++){
      float f0=fo_w[((0*16+u)*16+v)*2+w], f1=fo_w[((1*16+u)*16+v)*2+w];
      float f2=fo_w[((2*16+u)*16+v)*2+w], f3=fo_w[((3*16+u)*16+v)*2+w];
      float f4=fo_w[((4*16+u)*16+v)*2+w];
      atomicAdd(&outs0[w], s00*f0 + s220*f1);
      #pragma unroll
      for(int k=0;k<5;k++)
        atomicAdd(&outs2[w*5+k], s022[k]*f2 + s202[k]*f3 + s222[k]*f4);
    }
    float f5=fo_w[((5*16+u)*16+v)*2+0];
    #pragma unroll
    for(int k=0;k<9;k++) atomicAdd(&outs4[k], s224[k]*f5);
  }
  __syncthreads();

  if(tid<2) vv[tid]=outs0[tid];
  else if(tid<12) vv[tid]=outs2[tid-2];
  else if(tid<21) vv[tid]=outs4[tid-12];
  __syncthreads();
  if(tid<81){
    float a=0;
    for(int q=0;q<21;q++) a+=vv[q]*B21s[q*81+tid];
    stf[tid]=a;
  }
  __syncthreads();
  {
    const int MI[6]={0,1,2,1,0,0}, MJ[6]={0,1,2,2,2,1};
    const float MF[6]={1.f,1.f,1.f,1.4142135623730951f,1.4142135623730951f,1.4142135623730951f};
    if(tid<36){
      int p=tid/6, q=tid%6;
      Cm[tid]=stf[MI[p]*27+MJ[p]*9+MI[q]*3+MJ[q]]*MF[p]*MF[q];
    }
  }
  __syncthreads();
  if(tid<36){
    int p=tid/6, q=tid%6; float a=0;
    for(int r=0;r<6;r++) a+=Cm[p*6+r]*Cm[r*6+q];
    out[(size_t)g*36+tid]=a;
  }
}

// ============================ kernel_launch ============================
extern "C" void kernel_launch(void* const* d_in, const int* in_sizes, int n_in,
                              void* d_out, int out_size, void* d_ws, size_t ws_size,
                              hipStream_t stream)
{
  const float* positions=(const float*)d_in[0];
  const float* node_attrs=(const float*)d_in[1];
  const float* edge_attr=(const float*)d_in[2];
  const float* shifts=(const float*)d_in[3];
  const float* W_embed=(const float*)d_in[4];
  const float* b_embed=(const float*)d_in[5];
  const float* up1_w=(const float*)d_in[6];
  const float* mlp1_w1=(const float*)d_in[7];
  const float* mlp1_w2=(const float*)d_in[8];
  const float* lin1_w=(const float*)d_in[9];
  const float* lin1_b=(const float*)d_in[10];
  const float* up2_w=(const float*)d_in[11];
  const float* mlp2_w1=(const float*)d_in[12];
  const float* mlp2_w2=(const float*)d_in[13];
  const float* lin2_w=(const float*)d_in[14];
  const float* lin2_b=(const float*)d_in[15];
  const float* ro_lin_w=(const float*)d_in[16];
  const float* ro_gate_w=(const float*)d_in[17];
  const float* ro_gate_b=(const float*)d_in[18];
  const float* ro_lin2_w=(const float*)d_in[19];
  const float* glin_w0=(const float*)d_in[20];
  const float* glin_b0=(const float*)d_in[21];
  const float* glin_w2=(const float*)d_in[22];
  const float* prod_pw2=(const float*)d_in[23];
  const float* prod_pw3=(const float*)d_in[24];
  const float* prod_lin=(const float*)d_in[25];
  const float* fo_w=(const float*)d_in[26];
  const int* edge_index=(const int*)d_in[27];
  const int* batch=(const int*)d_in[28];
  const int N=in_sizes[1];
  const int E=in_sizes[2];
  const int G=128;
  float* out=(float*)d_out;

  // ---- workspace layout (floats); sort bufs; Tbl last, optional ----
  float* p=(float*)d_ws;
  float* shb=p;    p+=(size_t)12*E;
  float* efb=p;    p+=(size_t)12*E;
  float* bufA=p;   p+=(size_t)N*576;
  float* bufB=p;   p+=(size_t)N*576;
  float* gatesb=p; p+=(size_t)N*128;
  float* M123=p;   p+=3*4096;
  float* Svec=p;   p+=64;
  float* Tvec=p;   p+=64;
  float* bias2=p;  p+=64;
  float* m2T1=p;   p+=16384;
  float* m2T2=p;   p+=49152;
  float* gsum=p;   p+=(size_t)G*576;
  float* cntb=p;   p+=G;
  int* offs=(int*)p;   p+=N;
  int* posOf=(int*)p;  p+=E;
  int* sndS=(int*)p;   p+=E;
  int* rcvS=(int*)p;   p+=E;
  size_t baseNeed=(size_t)(p-(float*)d_ws)*sizeof(float);
  if(baseNeed>ws_size) return;
  float* Tbl=p;
  bool useTbl = (baseNeed + (size_t)96*E*sizeof(float)) <= ws_size;
  if(!useTbl) Tbl=nullptr;

  // ---- constant Wigner-3j tables ----
  WAll wa; Wg wg;
  {
    float t000[1],t011[9],t022[25],t101[9],t110[9],t112[45],t121[45],t202[25],t211[45],t220[25],t222[125],t224[225];
    real_w3j(0,0,0,t000); real_w3j(0,1,1,t011); real_w3j(0,2,2,t022);
    real_w3j(1,0,1,t101); real_w3j(1,1,0,t110); real_w3j(1,1,2,t112); real_w3j(1,2,1,t121);
    real_w3j(2,0,2,t202); real_w3j(2,1,1,t211); real_w3j(2,2,0,t220); real_w3j(2,2,2,t222); real_w3j(2,2,4,t224);
    wa.w000=t000[0];
    std::memcpy(wa.w011,t011,sizeof t011); std::memcpy(wa.w022,t022,sizeof t022);
    std::memcpy(wa.w101,t101,sizeof t101); std::memcpy(wa.w110,t110,sizeof t110);
    std::memcpy(wa.w112,t112,sizeof t112); std::memcpy(wa.w121,t121,sizeof t121);
    std::memcpy(wa.w202,t202,sizeof t202); std::memcpy(wa.w211,t211,sizeof t211);
    std::memcpy(wa.w220,t220,sizeof t220); std::memcpy(wa.w222,t222,sizeof t222);
    wg.w000=t000[0];
    std::memcpy(wg.w022,t022,sizeof t022); std::memcpy(wg.w202,t202,sizeof t202);
    std::memcpy(wg.w220,t220,sizeof t220); std::memcpy(wg.w222,t222,sizeof t222);
    std::memcpy(wg.w224,t224,sizeof t224);
  }

  // ---- pipeline ----
  k_prep<<<49,256,0,stream>>>(W_embed,b_embed,up1_w,lin1_w,lin1_b,up2_w,M123,Svec,Tvec,bias2);
  k_shuf<<<256,256,0,stream>>>(mlp1_w2,mlp2_w2,m2T1,m2T2);

  // counting sort of edges by receiver (in-place parallel scan, no memcpy)
  hipMemsetAsync(offs,0,(size_t)N*sizeof(int),stream);
  k_hist<<<(E+255)/256,256,0,stream>>>(edge_index,offs,E);
  k_scan<<<1,256,0,stream>>>(offs,N);
  k_scatter<<<(E+255)/256,256,0,stream>>>(edge_index,offs,posOf,sndS,rcvS,E);

  k_geom<<<(E+255)/256,256,0,stream>>>(positions,shifts,edge_attr,edge_index,posOf,shb,efb,Tbl,E,wa);

  hipMemsetAsync(bufA,0,(size_t)N*576*sizeof(float),stream);
  const int eblocks=1280;
  if(useTbl)
    k_edge1<1><<<eblocks,256,0,stream>>>(node_attrs,Svec,Tvec,mlp1_w1,m2T1,shb,Tbl,efb,sndS,rcvS,bufA,E,wa);
  else
    k_edge1<0><<<eblocks,256,0,stream>>>(node_attrs,Svec,Tvec,mlp1_w1,m2T1,shb,Tbl,efb,sndS,rcvS,bufA,E,wa);

  dim3 ngrid((N+15)/16,9);
  k_node<0><<<ngrid,256,0,stream>>>(bufA,bufB,M123,bias2,nullptr,nullptr,N,1.0f);       // agg1 -> ups2

  hipMemsetAsync(bufA,0,(size_t)N*576*sizeof(float),stream);
  if(useTbl)
    k_edge2<1><<<eblocks,256,0,stream>>>(bufB,mlp2_w1,m2T2,shb,Tbl,efb,sndS,rcvS,bufA,E,wa);
  else
    k_edge2<0><<<eblocks,256,0,stream>>>(bufB,mlp2_w1,m2T2,shb,Tbl,efb,sndS,rcvS,bufA,E,wa);

  k_node<1><<<ngrid,256,0,stream>>>(bufA,bufB,lin2_w,lin2_b,nullptr,nullptr,N,0.1f);    // agg2 -> xs
  k_gates<<<(N+15)/16,256,0,stream>>>(bufB,ro_gate_w,ro_gate_b,gatesb,N);
  k_node<2><<<ngrid,256,0,stream>>>(bufB,bufA,ro_lin_w,nullptr,gatesb,nullptr,N,1.0f);  // xs -> y

  hipMemsetAsync(gsum,0,((size_t)G*576+G)*sizeof(float),stream);
  k_cnt<<<(N+255)/256,256,0,stream>>>(batch,cntb,N);
  k_node<3><<<ngrid,256,0,stream>>>(bufA,gsum,ro_lin2_w,nullptr,nullptr,batch,N,1.0f);  // y -> gsum

  k_graph<<<G,256,0,stream>>>(gsum,cntb,glin_w0,glin_b0,glin_w2,prod_pw2,prod_pw3,prod_lin,fo_w,out,wg);
}